// Round 1
// baseline (1388.892 us; speedup 1.0000x reference)
//
#include <hip/hip_runtime.h>
#include <hip/hip_bf16.h>

#define N_NODES 50000
#define N_EDGES 1600000
#define CH 512

// ---------------- edge bucketing (counting sort by row) ----------------

__global__ __launch_bounds__(256) void hist_kernel(const int* __restrict__ row,
                                                   int* __restrict__ counts) {
    int e = blockIdx.x * 256 + threadIdx.x;
    if (e < N_EDGES) atomicAdd(&counts[row[e]], 1);
}

__global__ __launch_bounds__(1024) void scan_kernel(const int* __restrict__ counts,
                                                    int* __restrict__ offsets,
                                                    int* __restrict__ nxt) {
    __shared__ int partials[1024];
    const int t = threadIdx.x;
    const int CHUNK = (N_NODES + 1023) / 1024;  // 49
    int start = t * CHUNK;
    int end   = min(start + CHUNK, N_NODES);
    int sum = 0;
    for (int i = start; i < end; ++i) sum += counts[i];
    partials[t] = sum;
    __syncthreads();
    // Hillis-Steele inclusive scan over 1024 partials
    for (int d = 1; d < 1024; d <<= 1) {
        int v = (t >= d) ? partials[t - d] : 0;
        __syncthreads();
        partials[t] += v;
        __syncthreads();
    }
    int base = (t == 0) ? 0 : partials[t - 1];
    for (int i = start; i < end; ++i) {
        offsets[i] = base;
        nxt[i]     = base;
        base += counts[i];
    }
    if (start < N_NODES && end == N_NODES) offsets[N_NODES] = base;
}

__global__ __launch_bounds__(256) void scatter_kernel(const int* __restrict__ row,
                                                      const int* __restrict__ col,
                                                      const float* __restrict__ val,
                                                      int* __restrict__ nxt,
                                                      int* __restrict__ scol,
                                                      float* __restrict__ sval) {
    int e = blockIdx.x * 256 + threadIdx.x;
    if (e < N_EDGES) {
        int r = row[e];
        int p = atomicAdd(&nxt[r], 1);
        scol[p] = col[e];
        sval[p] = val[e];
    }
}

// ---------------- dense projection: support = x @ W (fp32 vector) ----------------
// BM=BN=128, BK=16, 256 threads, 8x8 microtile per thread.

__global__ __launch_bounds__(256) void gemm_kernel(const float* __restrict__ X,
                                                   const float* __restrict__ W,
                                                   float* __restrict__ S) {
    __shared__ float As[16][132];  // [k][m], padded
    __shared__ float Bs[16][132];  // [k][n], padded

    const int tid = threadIdx.x;
    const int m0 = blockIdx.x * 128;
    const int n0 = blockIdx.y * 128;
    const int tx = tid & 15;   // n dim
    const int ty = tid >> 4;   // m dim

    // A staging: 128 rows x 16 k = 2048 floats; each thread 2x float4 of one row-half
    const int arow = tid >> 1;
    const int ak   = (tid & 1) * 8;
    // B staging: 16 rows x 128 n; each thread 2x float4
    const int brow = tid >> 4;
    const int bcol = (tid & 15) * 8;

    float acc[8][8];
#pragma unroll
    for (int i = 0; i < 8; ++i)
#pragma unroll
        for (int j = 0; j < 8; ++j) acc[i][j] = 0.f;

    for (int k0 = 0; k0 < CH; k0 += 16) {
        float4 a0 = {0,0,0,0}, a1 = {0,0,0,0};
        const int gm = m0 + arow;
        if (gm < N_NODES) {
            a0 = *(const float4*)&X[(size_t)gm * CH + k0 + ak];
            a1 = *(const float4*)&X[(size_t)gm * CH + k0 + ak + 4];
        }
        const float4 b0 = *(const float4*)&W[(size_t)(k0 + brow) * CH + n0 + bcol];
        const float4 b1 = *(const float4*)&W[(size_t)(k0 + brow) * CH + n0 + bcol + 4];

        __syncthreads();  // previous tile fully consumed
        As[ak + 0][arow] = a0.x;
        As[ak + 1][arow] = a0.y;
        As[ak + 2][arow] = a0.z;
        As[ak + 3][arow] = a0.w;
        As[ak + 4][arow] = a1.x;
        As[ak + 5][arow] = a1.y;
        As[ak + 6][arow] = a1.z;
        As[ak + 7][arow] = a1.w;
        *(float4*)&Bs[brow][bcol]     = b0;
        *(float4*)&Bs[brow][bcol + 4] = b1;
        __syncthreads();

#pragma unroll
        for (int kk = 0; kk < 16; ++kk) {
            const float4 av0 = *(const float4*)&As[kk][ty * 8];
            const float4 av1 = *(const float4*)&As[kk][ty * 8 + 4];
            const float4 bv0 = *(const float4*)&Bs[kk][tx * 8];
            const float4 bv1 = *(const float4*)&Bs[kk][tx * 8 + 4];
            const float a[8] = {av0.x, av0.y, av0.z, av0.w, av1.x, av1.y, av1.z, av1.w};
            const float b[8] = {bv0.x, bv0.y, bv0.z, bv0.w, bv1.x, bv1.y, bv1.z, bv1.w};
#pragma unroll
            for (int i = 0; i < 8; ++i)
#pragma unroll
                for (int j = 0; j < 8; ++j) acc[i][j] += a[i] * b[j];
        }
    }

#pragma unroll
    for (int i = 0; i < 8; ++i) {
        const int gm = m0 + ty * 8 + i;
        if (gm < N_NODES) {
            float4 o0 = {acc[i][0], acc[i][1], acc[i][2], acc[i][3]};
            float4 o1 = {acc[i][4], acc[i][5], acc[i][6], acc[i][7]};
            *(float4*)&S[(size_t)gm * CH + n0 + tx * 8]     = o0;
            *(float4*)&S[(size_t)gm * CH + n0 + tx * 8 + 4] = o1;
        }
    }
}

// ---------------- SpMM: out[r] = sum_e val_e * support[col_e] ----------------
// one block (128 threads, float4 each) per output row

__global__ __launch_bounds__(128) void spmm_kernel(const int* __restrict__ offsets,
                                                   const int* __restrict__ scol,
                                                   const float* __restrict__ sval,
                                                   const float* __restrict__ S,
                                                   float* __restrict__ out) {
    const int r = blockIdx.x;
    const int c = threadIdx.x * 4;
    const int start = offsets[r];
    const int end   = offsets[r + 1];

    float4 acc = {0.f, 0.f, 0.f, 0.f};
    int e = start;
    for (; e + 1 < end; e += 2) {
        const int   c0 = scol[e];
        const float v0 = sval[e];
        const int   c1 = scol[e + 1];
        const float v1 = sval[e + 1];
        const float4 s0 = *(const float4*)&S[(size_t)c0 * CH + c];
        const float4 s1 = *(const float4*)&S[(size_t)c1 * CH + c];
        acc.x += v0 * s0.x; acc.y += v0 * s0.y; acc.z += v0 * s0.z; acc.w += v0 * s0.w;
        acc.x += v1 * s1.x; acc.y += v1 * s1.y; acc.z += v1 * s1.z; acc.w += v1 * s1.w;
    }
    if (e < end) {
        const int   c0 = scol[e];
        const float v0 = sval[e];
        const float4 s0 = *(const float4*)&S[(size_t)c0 * CH + c];
        acc.x += v0 * s0.x; acc.y += v0 * s0.y; acc.z += v0 * s0.z; acc.w += v0 * s0.w;
    }
    *(float4*)&out[(size_t)r * CH + c] = acc;
}

// ---------------- launch ----------------

extern "C" void kernel_launch(void* const* d_in, const int* in_sizes, int n_in,
                              void* d_out, int out_size, void* d_ws, size_t ws_size,
                              hipStream_t stream) {
    const float* x        = (const float*)d_in[0];
    const float* adj_vals = (const float*)d_in[1];
    const int*   edge_row = (const int*)d_in[2];
    const int*   edge_col = (const int*)d_in[3];
    const float* weight   = (const float*)d_in[4];
    float* out = (float*)d_out;

    // workspace carve-up (256B aligned)
    auto align256 = [](size_t v) { return (v + 255) & ~(size_t)255; };
    char* ws = (char*)d_ws;
    size_t off = 0;
    float* support = (float*)(ws + off); off = align256(off + (size_t)N_NODES * CH * sizeof(float));
    int*   counts  = (int*)(ws + off);   off = align256(off + (size_t)N_NODES * sizeof(int));
    int*   offsets = (int*)(ws + off);   off = align256(off + (size_t)(N_NODES + 1) * sizeof(int));
    int*   nxt     = (int*)(ws + off);   off = align256(off + (size_t)N_NODES * sizeof(int));
    int*   scol    = (int*)(ws + off);   off = align256(off + (size_t)N_EDGES * sizeof(int));
    float* sval    = (float*)(ws + off); off = align256(off + (size_t)N_EDGES * sizeof(float));

    // ws is poisoned 0xAA before every call: zero the histogram
    hipMemsetAsync(counts, 0, (size_t)N_NODES * sizeof(int), stream);

    const int EB = (N_EDGES + 255) / 256;
    hist_kernel<<<EB, 256, 0, stream>>>(edge_row, counts);
    scan_kernel<<<1, 1024, 0, stream>>>(counts, offsets, nxt);
    scatter_kernel<<<EB, 256, 0, stream>>>(edge_row, edge_col, adj_vals, nxt, scol, sval);

    dim3 ggrid((N_NODES + 127) / 128, CH / 128);
    gemm_kernel<<<ggrid, 256, 0, stream>>>(x, weight, support);

    spmm_kernel<<<N_NODES, 128, 0, stream>>>(offsets, scol, sval, support, out);
}

// Round 3
// 885.753 us; speedup vs baseline: 1.5680x; 1.5680x over previous
//
#include <hip/hip_runtime.h>
#include <hip/hip_bf16.h>

#define N_NODES 50000
#define N_EDGES 1600000
#define CH 512
#define SCAN_B 196  // ceil(50000/256)

typedef short short8v __attribute__((ext_vector_type(8)));
typedef float f32x4 __attribute__((ext_vector_type(4)));
typedef unsigned short ushort8v __attribute__((ext_vector_type(8)));

#define GLOAD_LDS16(gptr, lptr)                                                        \
    __builtin_amdgcn_global_load_lds((const __attribute__((address_space(1))) void*)(gptr), \
                                     (__attribute__((address_space(3))) void*)(lptr), 16, 0, 0)

// round-to-nearest-even fp32 -> bf16 bits (finite inputs)
__device__ inline unsigned short f2bf(float x) {
    unsigned u = __float_as_uint(x);
    u = (u + 0x7FFF + ((u >> 16) & 1)) >> 16;
    return (unsigned short)u;
}
__device__ inline float bf2f(unsigned short b) {
    return __uint_as_float(((unsigned)b) << 16);
}

// ---------------- edge bucketing (counting sort by row) ----------------

__global__ __launch_bounds__(256) void hist_kernel(const int* __restrict__ row,
                                                   int* __restrict__ counts) {
    int e = blockIdx.x * 256 + threadIdx.x;
    if (e < N_EDGES) atomicAdd(&counts[row[e]], 1);
}

__global__ __launch_bounds__(256) void bsum_kernel(const int* __restrict__ counts,
                                                   int* __restrict__ bsum) {
    __shared__ int red[256];
    int i = blockIdx.x * 256 + threadIdx.x;
    red[threadIdx.x] = (i < N_NODES) ? counts[i] : 0;
    __syncthreads();
    for (int s = 128; s > 0; s >>= 1) {
        if (threadIdx.x < s) red[threadIdx.x] += red[threadIdx.x + s];
        __syncthreads();
    }
    if (threadIdx.x == 0) bsum[blockIdx.x] = red[0];
}

__global__ __launch_bounds__(256) void bscan_kernel(const int* __restrict__ bsum,
                                                    int* __restrict__ bbase) {
    __shared__ int sc[256];
    int t = threadIdx.x;
    int v = (t < SCAN_B) ? bsum[t] : 0;
    sc[t] = v;
    __syncthreads();
    for (int d = 1; d < 256; d <<= 1) {
        int a = (t >= d) ? sc[t - d] : 0;
        __syncthreads();
        sc[t] += a;
        __syncthreads();
    }
    if (t < SCAN_B) bbase[t] = sc[t] - v;  // exclusive
}

__global__ __launch_bounds__(256) void offsets_kernel(const int* __restrict__ counts,
                                                      const int* __restrict__ bbase,
                                                      int* __restrict__ offsets,
                                                      int* __restrict__ nxt) {
    __shared__ int sc[256];
    int t = threadIdx.x;
    int i = blockIdx.x * 256 + t;
    int v = (i < N_NODES) ? counts[i] : 0;
    sc[t] = v;
    __syncthreads();
    for (int d = 1; d < 256; d <<= 1) {
        int a = (t >= d) ? sc[t - d] : 0;
        __syncthreads();
        sc[t] += a;
        __syncthreads();
    }
    int off = bbase[blockIdx.x] + sc[t] - v;
    if (i < N_NODES) { offsets[i] = off; nxt[i] = off; }
    if (i == 0) offsets[N_NODES] = N_EDGES;
}

__global__ __launch_bounds__(256) void scatter_kernel(const int* __restrict__ row,
                                                      const int* __restrict__ col,
                                                      const float* __restrict__ val,
                                                      int* __restrict__ nxt,
                                                      int2* __restrict__ ep) {
    int e = blockIdx.x * 256 + threadIdx.x;
    if (e < N_EDGES) {
        int r = row[e];
        int p = atomicAdd(&nxt[r], 1);
        ep[p] = make_int2(col[e], __float_as_int(val[e]));
    }
}

// ---------------- W pre-transform: Wc[kt][n][64] bf16 (hi k0..31 | lo k0..31) ----------------
// natural (unswizzled) slot order; GEMM pre-swizzles the global source address.

__global__ __launch_bounds__(256) void prep_w(const float* __restrict__ W,
                                              unsigned short* __restrict__ Wc) {
    __shared__ float tile[32][65];
    const int kt = blockIdx.x;       // 16 K-tiles of 32
    const int nb = blockIdx.y * 64;  // 8 col groups of 64
    const int t = threadIdx.x;
    const int nl = t & 63, kl = t >> 6;
#pragma unroll
    for (int p = 0; p < 8; ++p) {
        int k = p * 4 + kl;
        tile[k][nl] = W[(size_t)(kt * 32 + k) * CH + nb + nl];
    }
    __syncthreads();
    const int n_local = t >> 2, j = t & 3;
    ushort8v hi, lo;
#pragma unroll
    for (int q = 0; q < 8; ++q) {
        float x = tile[j * 8 + q][n_local];
        unsigned short h = f2bf(x);
        hi[q] = h;
        lo[q] = f2bf(x - bf2f(h));
    }
    size_t base = ((size_t)kt * 512 + nb + n_local) * 64 + j * 8;
    *(ushort8v*)&Wc[base] = hi;       // hi slot j
    *(ushort8v*)&Wc[base + 32] = lo;  // lo slot 4+j
}

// ---------------- GEMM: support = X @ W via bf16x3 MFMA ----------------
// BM=BN=128, BK=32, 256 threads (4 waves 2x2, 64x64 each).
// LDS rows = 128B (32 hi bf16 | 32 lo bf16), 16B slots XOR-swizzled: slot' = slot ^ (row&7).

__global__ __launch_bounds__(256) void gemm_kernel(const float* __restrict__ X,
                                                   const unsigned short* __restrict__ Wc,
                                                   float* __restrict__ S) {
    __shared__ __align__(16) unsigned short Al[128 * 64];
    __shared__ __align__(16) unsigned short Bl[128 * 64];

    const int tid = threadIdx.x;
    const int wave = tid >> 6;
    const int lane = tid & 63;
    const int wm = (wave >> 1) * 64;
    const int wn = (wave & 1) * 64;
    const int m0 = blockIdx.x * 128;
    const int n0 = blockIdx.y * 128;

    // B staging lane-constant source offset (ushort units): row 64, slot 8
    const int lrow = lane >> 3, lslot = lane & 7;
    const int b_lane_off = lrow * 64 + ((lslot ^ lrow) << 3);

    // A staging: thread -> (row, k-half)
    const int srow = tid >> 1;
    const int skh = tid & 1;
    const int gm_s = m0 + srow;
    const int r7 = srow & 7;

    f32x4 acc[4][4] = {};

    for (int kt = 0; kt < 16; ++kt) {
        // ---- B: async global->LDS, pre-swizzled source, linear dest ----
        const unsigned short* bsrc = Wc + ((size_t)kt * 512 + n0 + wave * 32) * 64 + b_lane_off;
        unsigned short* bdst = &Bl[(wave * 32) * 64];
        GLOAD_LDS16(bsrc, bdst);
        GLOAD_LDS16(bsrc + 512, bdst + 512);
        GLOAD_LDS16(bsrc + 1024, bdst + 1024);
        GLOAD_LDS16(bsrc + 1536, bdst + 1536);

        // ---- A: reg-stage fp32 -> bf16 hi/lo, swizzled ds_write ----
        float xv[16];
        if (gm_s < N_NODES) {
            const float* xp = &X[(size_t)gm_s * CH + kt * 32 + skh * 16];
            *(float4*)&xv[0]  = *(const float4*)&xp[0];
            *(float4*)&xv[4]  = *(const float4*)&xp[4];
            *(float4*)&xv[8]  = *(const float4*)&xp[8];
            *(float4*)&xv[12] = *(const float4*)&xp[12];
        } else {
#pragma unroll
            for (int q = 0; q < 16; ++q) xv[q] = 0.f;
        }
        ushort8v h0, h1, l0, l1;
#pragma unroll
        for (int q = 0; q < 8; ++q) {
            unsigned short h = f2bf(xv[q]);
            h0[q] = h;
            l0[q] = f2bf(xv[q] - bf2f(h));
            unsigned short h2 = f2bf(xv[8 + q]);
            h1[q] = h2;
            l1[q] = f2bf(xv[8 + q] - bf2f(h2));
        }
        {
            const int s0 = skh * 2, s1 = skh * 2 + 1;
            unsigned short* arow = &Al[srow * 64];
            *(ushort8v*)&arow[((s0 ^ r7) << 3)] = h0;
            *(ushort8v*)&arow[((s1 ^ r7) << 3)] = h1;
            *(ushort8v*)&arow[(((s0 | 4) ^ r7) << 3)] = l0;
            *(ushort8v*)&arow[(((s1 | 4) ^ r7) << 3)] = l1;
        }
        __syncthreads();

        // ---- fragments + 48 MFMA ----
        const int fr = lane & 15;
        const int fs = lane >> 4;
        const int fx = lane & 7;
        short8v ahi[4], alo[4];
#pragma unroll
        for (int mi = 0; mi < 4; ++mi) {
            const unsigned short* ar = &Al[(wm + mi * 16 + fr) * 64];
            ahi[mi] = *(const short8v*)&ar[((fs ^ fx) << 3)];
            alo[mi] = *(const short8v*)&ar[(((fs | 4) ^ fx) << 3)];
        }
#pragma unroll
        for (int ni = 0; ni < 4; ++ni) {
            const unsigned short* br = &Bl[(wn + ni * 16 + fr) * 64];
            short8v bhi = *(const short8v*)&br[((fs ^ fx) << 3)];
            short8v blo = *(const short8v*)&br[(((fs | 4) ^ fx) << 3)];
#pragma unroll
            for (int mi = 0; mi < 4; ++mi) {
                acc[mi][ni] = __builtin_amdgcn_mfma_f32_16x16x32_bf16(ahi[mi], bhi, acc[mi][ni], 0, 0, 0);
                acc[mi][ni] = __builtin_amdgcn_mfma_f32_16x16x32_bf16(ahi[mi], blo, acc[mi][ni], 0, 0, 0);
                acc[mi][ni] = __builtin_amdgcn_mfma_f32_16x16x32_bf16(alo[mi], bhi, acc[mi][ni], 0, 0, 0);
            }
        }
        __syncthreads();
    }

    // ---- store C: col = lane&15, row = (lane>>4)*4 + reg ----
    const int crow = (lane >> 4) * 4;
    const int ccol = lane & 15;
#pragma unroll
    for (int mi = 0; mi < 4; ++mi) {
#pragma unroll
        for (int r = 0; r < 4; ++r) {
            int gm = m0 + wm + mi * 16 + crow + r;
            if (gm < N_NODES) {
#pragma unroll
                for (int ni = 0; ni < 4; ++ni) {
                    S[(size_t)gm * CH + n0 + wn + ni * 16 + ccol] = acc[mi][ni][r];
                }
            }
        }
    }
}

// ---------------- SpMM: out[r] = sum_e val_e * support[col_e] ----------------

__global__ __launch_bounds__(128) void spmm_kernel(const int* __restrict__ offsets,
                                                   const int2* __restrict__ ep,
                                                   const float* __restrict__ S,
                                                   float* __restrict__ out) {
    const int r = blockIdx.x;
    const int c = threadIdx.x * 4;
    const int start = offsets[r];
    const int end = offsets[r + 1];

    float4 acc = {0.f, 0.f, 0.f, 0.f};
    int e = start;
    for (; e + 1 < end; e += 2) {
        const int2 e0 = ep[e];
        const int2 e1 = ep[e + 1];
        const float v0 = __int_as_float(e0.y);
        const float v1 = __int_as_float(e1.y);
        const float4 s0 = *(const float4*)&S[(size_t)e0.x * CH + c];
        const float4 s1 = *(const float4*)&S[(size_t)e1.x * CH + c];
        acc.x += v0 * s0.x; acc.y += v0 * s0.y; acc.z += v0 * s0.z; acc.w += v0 * s0.w;
        acc.x += v1 * s1.x; acc.y += v1 * s1.y; acc.z += v1 * s1.z; acc.w += v1 * s1.w;
    }
    if (e < end) {
        const int2 e0 = ep[e];
        const float v0 = __int_as_float(e0.y);
        const float4 s0 = *(const float4*)&S[(size_t)e0.x * CH + c];
        acc.x += v0 * s0.x; acc.y += v0 * s0.y; acc.z += v0 * s0.z; acc.w += v0 * s0.w;
    }
    *(float4*)&out[(size_t)r * CH + c] = acc;
}

// ---------------- launch ----------------

extern "C" void kernel_launch(void* const* d_in, const int* in_sizes, int n_in,
                              void* d_out, int out_size, void* d_ws, size_t ws_size,
                              hipStream_t stream) {
    const float* x        = (const float*)d_in[0];
    const float* adj_vals = (const float*)d_in[1];
    const int*   edge_row = (const int*)d_in[2];
    const int*   edge_col = (const int*)d_in[3];
    const float* weight   = (const float*)d_in[4];
    float* out = (float*)d_out;

    auto align256 = [](size_t v) { return (v + 255) & ~(size_t)255; };
    char* ws = (char*)d_ws;
    size_t off = 0;
    float* support = (float*)(ws + off);          off = align256(off + (size_t)N_NODES * CH * sizeof(float));
    int*   counts  = (int*)(ws + off);            off = align256(off + (size_t)N_NODES * sizeof(int));
    int*   offsets = (int*)(ws + off);            off = align256(off + (size_t)(N_NODES + 1) * sizeof(int));
    int*   nxt     = (int*)(ws + off);            off = align256(off + (size_t)N_NODES * sizeof(int));
    int2*  ep      = (int2*)(ws + off);           off = align256(off + (size_t)N_EDGES * sizeof(int2));
    unsigned short* Wc = (unsigned short*)(ws + off); off = align256(off + (size_t)16 * 512 * 64 * sizeof(unsigned short));
    int*   bsum    = (int*)(ws + off);            off = align256(off + (size_t)SCAN_B * sizeof(int));
    int*   bbase   = (int*)(ws + off);            off = align256(off + (size_t)SCAN_B * sizeof(int));

    hipMemsetAsync(counts, 0, (size_t)N_NODES * sizeof(int), stream);

    const int EB = (N_EDGES + 255) / 256;
    hist_kernel<<<EB, 256, 0, stream>>>(edge_row, counts);
    bsum_kernel<<<SCAN_B, 256, 0, stream>>>(counts, bsum);
    bscan_kernel<<<1, 256, 0, stream>>>(bsum, bbase);
    offsets_kernel<<<SCAN_B, 256, 0, stream>>>(counts, bbase, offsets, nxt);
    scatter_kernel<<<EB, 256, 0, stream>>>(edge_row, edge_col, adj_vals, nxt, ep);

    dim3 wgrid(16, 8);
    prep_w<<<wgrid, 256, 0, stream>>>(weight, Wc);

    dim3 ggrid((N_NODES + 127) / 128, CH / 128);
    gemm_kernel<<<ggrid, 256, 0, stream>>>(x, Wc, support);

    spmm_kernel<<<N_NODES, 128, 0, stream>>>(offsets, ep, support, out);
}

// Round 4
// 659.771 us; speedup vs baseline: 2.1051x; 1.3425x over previous
//
#include <hip/hip_runtime.h>
#include <hip/hip_bf16.h>

#define N_NODES 50000
#define N_EDGES 1600000
#define CH 512
#define SCAN_B 196  // ceil(50000/256)

typedef short short8v __attribute__((ext_vector_type(8)));
typedef float f32x4 __attribute__((ext_vector_type(4)));
typedef unsigned short ushort8v __attribute__((ext_vector_type(8)));
typedef _Float16 half8v __attribute__((ext_vector_type(8)));

#define GLOAD_LDS16(gptr, lptr)                                                        \
    __builtin_amdgcn_global_load_lds((const __attribute__((address_space(1))) void*)(gptr), \
                                     (__attribute__((address_space(3))) void*)(lptr), 16, 0, 0)

// round-to-nearest-even fp32 -> bf16 bits (finite inputs)
__device__ inline unsigned short f2bf(float x) {
    unsigned u = __float_as_uint(x);
    u = (u + 0x7FFF + ((u >> 16) & 1)) >> 16;
    return (unsigned short)u;
}
__device__ inline float bf2f(unsigned short b) {
    return __uint_as_float(((unsigned)b) << 16);
}
__device__ inline unsigned short f2h(float x) {
    union { _Float16 h; unsigned short u; } cv;
    cv.h = (_Float16)x;   // v_cvt_f16_f32, RNE
    return cv.u;
}

// ---------------- edge bucketing (counting sort by row) ----------------

__global__ __launch_bounds__(256) void hist_kernel(const int* __restrict__ row,
                                                   int* __restrict__ counts) {
    int e = blockIdx.x * 256 + threadIdx.x;
    if (e < N_EDGES) atomicAdd(&counts[row[e]], 1);
}

__global__ __launch_bounds__(256) void bsum_kernel(const int* __restrict__ counts,
                                                   int* __restrict__ bsum) {
    __shared__ int red[256];
    int i = blockIdx.x * 256 + threadIdx.x;
    red[threadIdx.x] = (i < N_NODES) ? counts[i] : 0;
    __syncthreads();
    for (int s = 128; s > 0; s >>= 1) {
        if (threadIdx.x < s) red[threadIdx.x] += red[threadIdx.x + s];
        __syncthreads();
    }
    if (threadIdx.x == 0) bsum[blockIdx.x] = red[0];
}

__global__ __launch_bounds__(256) void bscan_kernel(const int* __restrict__ bsum,
                                                    int* __restrict__ bbase) {
    __shared__ int sc[256];
    int t = threadIdx.x;
    int v = (t < SCAN_B) ? bsum[t] : 0;
    sc[t] = v;
    __syncthreads();
    for (int d = 1; d < 256; d <<= 1) {
        int a = (t >= d) ? sc[t - d] : 0;
        __syncthreads();
        sc[t] += a;
        __syncthreads();
    }
    if (t < SCAN_B) bbase[t] = sc[t] - v;  // exclusive
}

__global__ __launch_bounds__(256) void offsets_kernel(const int* __restrict__ counts,
                                                      const int* __restrict__ bbase,
                                                      int* __restrict__ offsets,
                                                      int* __restrict__ nxt) {
    __shared__ int sc[256];
    int t = threadIdx.x;
    int i = blockIdx.x * 256 + t;
    int v = (i < N_NODES) ? counts[i] : 0;
    sc[t] = v;
    __syncthreads();
    for (int d = 1; d < 256; d <<= 1) {
        int a = (t >= d) ? sc[t - d] : 0;
        __syncthreads();
        sc[t] += a;
        __syncthreads();
    }
    int off = bbase[blockIdx.x] + sc[t] - v;
    if (i < N_NODES) { offsets[i] = off; nxt[i] = off; }
    if (i == 0) offsets[N_NODES] = N_EDGES;
}

__global__ __launch_bounds__(256) void scatter_kernel(const int* __restrict__ row,
                                                      const int* __restrict__ col,
                                                      const float* __restrict__ val,
                                                      int* __restrict__ nxt,
                                                      int2* __restrict__ ep) {
    int e = blockIdx.x * 256 + threadIdx.x;
    if (e < N_EDGES) {
        int r = row[e];
        int p = atomicAdd(&nxt[r], 1);
        ep[p] = make_int2(col[e], __float_as_int(val[e]));
    }
}

// ---------------- W pre-transform: Wc[kt][n][64] bf16 (hi k0..31 | lo k0..31) ----------------

__global__ __launch_bounds__(256) void prep_w(const float* __restrict__ W,
                                              unsigned short* __restrict__ Wc) {
    __shared__ float tile[32][65];
    const int kt = blockIdx.x;       // 16 K-tiles of 32
    const int nb = blockIdx.y * 64;  // 8 col groups of 64
    const int t = threadIdx.x;
    const int nl = t & 63, kl = t >> 6;
#pragma unroll
    for (int p = 0; p < 8; ++p) {
        int k = p * 4 + kl;
        tile[k][nl] = W[(size_t)(kt * 32 + k) * CH + nb + nl];
    }
    __syncthreads();
    const int n_local = t >> 2, j = t & 3;
    ushort8v hi, lo;
#pragma unroll
    for (int q = 0; q < 8; ++q) {
        float x = tile[j * 8 + q][n_local];
        unsigned short h = f2bf(x);
        hi[q] = h;
        lo[q] = f2bf(x - bf2f(h));
    }
    size_t base = ((size_t)kt * 512 + nb + n_local) * 64 + j * 8;
    *(ushort8v*)&Wc[base] = hi;       // hi slot j
    *(ushort8v*)&Wc[base + 32] = lo;  // lo slot 4+j
}

// ---------------- GEMM: support(fp16) = X @ W via bf16x3 MFMA ----------------
// BM=BN=128, BK=32, 256 threads (4 waves 2x2, 64x64 each).
// LDS rows = 128B (32 hi bf16 | 32 lo bf16), 16B slots XOR-swizzled: slot' = slot ^ (row&7).

__global__ __launch_bounds__(256) void gemm_kernel(const float* __restrict__ X,
                                                   const unsigned short* __restrict__ Wc,
                                                   unsigned short* __restrict__ S) {
    __shared__ __align__(16) unsigned short Al[128 * 64];
    __shared__ __align__(16) unsigned short Bl[128 * 64];

    const int tid = threadIdx.x;
    const int wave = tid >> 6;
    const int lane = tid & 63;
    const int wm = (wave >> 1) * 64;
    const int wn = (wave & 1) * 64;
    const int m0 = blockIdx.x * 128;
    const int n0 = blockIdx.y * 128;

    // B staging lane-constant source offset (ushort units): row 64, slot 8
    const int lrow = lane >> 3, lslot = lane & 7;
    const int b_lane_off = lrow * 64 + ((lslot ^ lrow) << 3);

    // A staging: thread -> (row, k-half)
    const int srow = tid >> 1;
    const int skh = tid & 1;
    const int gm_s = m0 + srow;
    const int r7 = srow & 7;

    f32x4 acc[4][4] = {};

    for (int kt = 0; kt < 16; ++kt) {
        // ---- B: async global->LDS, pre-swizzled source, linear dest ----
        const unsigned short* bsrc = Wc + ((size_t)kt * 512 + n0 + wave * 32) * 64 + b_lane_off;
        unsigned short* bdst = &Bl[(wave * 32) * 64];
        GLOAD_LDS16(bsrc, bdst);
        GLOAD_LDS16(bsrc + 512, bdst + 512);
        GLOAD_LDS16(bsrc + 1024, bdst + 1024);
        GLOAD_LDS16(bsrc + 1536, bdst + 1536);

        // ---- A: reg-stage fp32 -> bf16 hi/lo, swizzled ds_write ----
        float xv[16];
        if (gm_s < N_NODES) {
            const float* xp = &X[(size_t)gm_s * CH + kt * 32 + skh * 16];
            *(float4*)&xv[0]  = *(const float4*)&xp[0];
            *(float4*)&xv[4]  = *(const float4*)&xp[4];
            *(float4*)&xv[8]  = *(const float4*)&xp[8];
            *(float4*)&xv[12] = *(const float4*)&xp[12];
        } else {
#pragma unroll
            for (int q = 0; q < 16; ++q) xv[q] = 0.f;
        }
        ushort8v h0, h1, l0, l1;
#pragma unroll
        for (int q = 0; q < 8; ++q) {
            unsigned short h = f2bf(xv[q]);
            h0[q] = h;
            l0[q] = f2bf(xv[q] - bf2f(h));
            unsigned short h2 = f2bf(xv[8 + q]);
            h1[q] = h2;
            l1[q] = f2bf(xv[8 + q] - bf2f(h2));
        }
        {
            const int s0 = skh * 2, s1 = skh * 2 + 1;
            unsigned short* arow = &Al[srow * 64];
            *(ushort8v*)&arow[((s0 ^ r7) << 3)] = h0;
            *(ushort8v*)&arow[((s1 ^ r7) << 3)] = h1;
            *(ushort8v*)&arow[(((s0 | 4) ^ r7) << 3)] = l0;
            *(ushort8v*)&arow[(((s1 | 4) ^ r7) << 3)] = l1;
        }
        __syncthreads();

        // ---- fragments + 48 MFMA ----
        const int fr = lane & 15;
        const int fs = lane >> 4;
        const int fx = lane & 7;
        short8v ahi[4], alo[4];
#pragma unroll
        for (int mi = 0; mi < 4; ++mi) {
            const unsigned short* ar = &Al[(wm + mi * 16 + fr) * 64];
            ahi[mi] = *(const short8v*)&ar[((fs ^ fx) << 3)];
            alo[mi] = *(const short8v*)&ar[(((fs | 4) ^ fx) << 3)];
        }
#pragma unroll
        for (int ni = 0; ni < 4; ++ni) {
            const unsigned short* br = &Bl[(wn + ni * 16 + fr) * 64];
            short8v bhi = *(const short8v*)&br[((fs ^ fx) << 3)];
            short8v blo = *(const short8v*)&br[(((fs | 4) ^ fx) << 3)];
#pragma unroll
            for (int mi = 0; mi < 4; ++mi) {
                acc[mi][ni] = __builtin_amdgcn_mfma_f32_16x16x32_bf16(ahi[mi], bhi, acc[mi][ni], 0, 0, 0);
                acc[mi][ni] = __builtin_amdgcn_mfma_f32_16x16x32_bf16(ahi[mi], blo, acc[mi][ni], 0, 0, 0);
                acc[mi][ni] = __builtin_amdgcn_mfma_f32_16x16x32_bf16(alo[mi], bhi, acc[mi][ni], 0, 0, 0);
            }
        }
        __syncthreads();
    }

    // ---- store C as fp16: col = lane&15, row = (lane>>4)*4 + reg ----
    const int crow = (lane >> 4) * 4;
    const int ccol = lane & 15;
#pragma unroll
    for (int mi = 0; mi < 4; ++mi) {
#pragma unroll
        for (int r = 0; r < 4; ++r) {
            int gm = m0 + wm + mi * 16 + crow + r;
            if (gm < N_NODES) {
#pragma unroll
                for (int ni = 0; ni < 4; ++ni) {
                    S[(size_t)gm * CH + n0 + wn + ni * 16 + ccol] = f2h(acc[mi][ni][r]);
                }
            }
        }
    }
}

// ---------------- SpMM: out[r] = sum_e val_e * support[col_e] ----------------
// one wave per row; lane covers 8 channels (half8 = 16B/lane); 4x edge unroll.

__global__ __launch_bounds__(128) void spmm_kernel(const int* __restrict__ offsets,
                                                   const int2* __restrict__ ep,
                                                   const unsigned short* __restrict__ S,
                                                   float* __restrict__ out) {
    const int r = blockIdx.x * 2 + (threadIdx.x >> 6);
    const int lane = threadIdx.x & 63;
    const int c = lane * 8;
    const int start = offsets[r];
    const int end = offsets[r + 1];

    float acc[8] = {0.f, 0.f, 0.f, 0.f, 0.f, 0.f, 0.f, 0.f};
    int e = start;
    for (; e + 3 < end; e += 4) {
        const int2 e0 = ep[e];
        const int2 e1 = ep[e + 1];
        const int2 e2 = ep[e + 2];
        const int2 e3 = ep[e + 3];
        const half8v s0 = *(const half8v*)&S[(size_t)e0.x * CH + c];
        const half8v s1 = *(const half8v*)&S[(size_t)e1.x * CH + c];
        const half8v s2 = *(const half8v*)&S[(size_t)e2.x * CH + c];
        const half8v s3 = *(const half8v*)&S[(size_t)e3.x * CH + c];
        const float v0 = __int_as_float(e0.y);
        const float v1 = __int_as_float(e1.y);
        const float v2 = __int_as_float(e2.y);
        const float v3 = __int_as_float(e3.y);
#pragma unroll
        for (int j = 0; j < 8; ++j) {
            acc[j] += v0 * (float)s0[j];
            acc[j] += v1 * (float)s1[j];
            acc[j] += v2 * (float)s2[j];
            acc[j] += v3 * (float)s3[j];
        }
    }
    for (; e < end; ++e) {
        const int2 e0 = ep[e];
        const half8v s0 = *(const half8v*)&S[(size_t)e0.x * CH + c];
        const float v0 = __int_as_float(e0.y);
#pragma unroll
        for (int j = 0; j < 8; ++j) acc[j] += v0 * (float)s0[j];
    }
    float4 o0 = {acc[0], acc[1], acc[2], acc[3]};
    float4 o1 = {acc[4], acc[5], acc[6], acc[7]};
    *(float4*)&out[(size_t)r * CH + c] = o0;
    *(float4*)&out[(size_t)r * CH + c + 4] = o1;
}

// ---------------- launch ----------------

extern "C" void kernel_launch(void* const* d_in, const int* in_sizes, int n_in,
                              void* d_out, int out_size, void* d_ws, size_t ws_size,
                              hipStream_t stream) {
    const float* x        = (const float*)d_in[0];
    const float* adj_vals = (const float*)d_in[1];
    const int*   edge_row = (const int*)d_in[2];
    const int*   edge_col = (const int*)d_in[3];
    const float* weight   = (const float*)d_in[4];
    float* out = (float*)d_out;

    auto align256 = [](size_t v) { return (v + 255) & ~(size_t)255; };
    char* ws = (char*)d_ws;
    size_t off = 0;
    unsigned short* support = (unsigned short*)(ws + off); off = align256(off + (size_t)N_NODES * CH * sizeof(unsigned short));
    int*   counts  = (int*)(ws + off);            off = align256(off + (size_t)N_NODES * sizeof(int));
    int*   offsets = (int*)(ws + off);            off = align256(off + (size_t)(N_NODES + 1) * sizeof(int));
    int*   nxt     = (int*)(ws + off);            off = align256(off + (size_t)N_NODES * sizeof(int));
    int2*  ep      = (int2*)(ws + off);           off = align256(off + (size_t)N_EDGES * sizeof(int2));
    unsigned short* Wc = (unsigned short*)(ws + off); off = align256(off + (size_t)16 * 512 * 64 * sizeof(unsigned short));
    int*   bsum    = (int*)(ws + off);            off = align256(off + (size_t)SCAN_B * sizeof(int));
    int*   bbase   = (int*)(ws + off);            off = align256(off + (size_t)SCAN_B * sizeof(int));

    hipMemsetAsync(counts, 0, (size_t)N_NODES * sizeof(int), stream);

    const int EB = (N_EDGES + 255) / 256;
    hist_kernel<<<EB, 256, 0, stream>>>(edge_row, counts);
    bsum_kernel<<<SCAN_B, 256, 0, stream>>>(counts, bsum);
    bscan_kernel<<<1, 256, 0, stream>>>(bsum, bbase);
    offsets_kernel<<<SCAN_B, 256, 0, stream>>>(counts, bbase, offsets, nxt);
    scatter_kernel<<<EB, 256, 0, stream>>>(edge_row, edge_col, adj_vals, nxt, ep);

    dim3 wgrid(16, 8);
    prep_w<<<wgrid, 256, 0, stream>>>(weight, Wc);

    dim3 ggrid((N_NODES + 127) / 128, CH / 128);
    gemm_kernel<<<ggrid, 256, 0, stream>>>(x, Wc, support);

    spmm_kernel<<<N_NODES / 2, 128, 0, stream>>>(offsets, ep, support, out);
}